// Round 15
// baseline (710.773 us; speedup 1.0000x reference)
//
#include <hip/hip_runtime.h>

// MultiHeadElman scan, R15: 2 chains/wave, full 32-dot per lane, NO combine.
// Chain A = lanes 0-31 (head 2k), chain B = lanes 32-63 (head 2k+1); each
// lane owns row cc = l&31 and computes the whole dot:
//   own 16-block pairs: pd = cvtpk(hn, dpp1(hn)) + 7x rot2 (R13 wrapped cover)
//   other 16-block:     permlane16_swap(pd) + 7x rot2 of it
// -> cross-lane depth 3 (was 4), permlane32-combine and fix-select GONE.
// wx: 4x mfma_f32_16x16x32_f16 per 16-step block (2 heads x 2 col-tiles),
// results transposed to wxT[64 rows][20] so each lane ds_read_b128's a 4-step
// quad of its own row one group ahead (R14-proven). x staged via
// global_load_lds, drained with counted vmcnt (R10-proven).

typedef __fp16 f16x2 __attribute__((ext_vector_type(2)));
typedef __fp16 f16x8 __attribute__((ext_vector_type(8)));
typedef float  f32x4 __attribute__((ext_vector_type(4)));
typedef unsigned int v2u __attribute__((ext_vector_type(2)));

constexpr int T_STEPS = 4096;
constexpr int B_SZ    = 4;
constexpr int D_SZ    = 2048;
constexpr int H_SZ    = 64;
constexpr int HD      = 32;
constexpr long ST     = (long)B_SZ * D_SZ;   // 8192 floats per t
constexpr int BLK     = 16;                  // steps per block
constexpr int WPAD    = 20;                  // wxT row pitch

typedef const __attribute__((address_space(1))) void* gas_t;
typedef __attribute__((address_space(3))) void*       las_t;

#if __has_builtin(__builtin_amdgcn_fdot2)
__device__ __forceinline__ float FDOT2(f16x2 a, f16x2 b, float c) {
    return __builtin_amdgcn_fdot2(a, b, c, false);
}
#else
__device__ __forceinline__ float FDOT2(f16x2 a, f16x2 b, float c) {
    return fmaf((float)a.x, (float)b.x, fmaf((float)a.y, (float)b.y, c));
}
#endif

// pair-rotation: lane c receives the pair register of lane (c+2D)&15.
template<bool RM, int D>
__device__ __forceinline__ f16x2 rot2(unsigned u) {
    constexpr int ctrl = 0x120 + (RM ? (16 - 2 * D) : (2 * D));
    const unsigned r = (unsigned)__builtin_amdgcn_update_dpp(
        (int)u, (int)u, ctrl, 0xF, 0xF, false);
    return __builtin_bit_cast(f16x2, r);
}
// neighbor: lane c receives lane (c+1)&15's value.
template<bool RM>
__device__ __forceinline__ float nexth(float v) {
    constexpr int ctrl = 0x120 + (RM ? 15 : 1);
    return __int_as_float(__builtin_amdgcn_update_dpp(
        __float_as_int(v), __float_as_int(v), ctrl, 0xF, 0xF, false));
}

union AF { f16x8 v; f16x2 pcs[4]; };

struct Ctx {
    f16x2 wo[8];            // own-block pair weights (wrapped cover)
    f16x2 wt[8];            // other-block pair weights
    AF bf[4];               // MFMA B frags: (hA,cb0),(hA,cb1),(hB,cb0),(hB,cb1)
    float bn[4];            // bias C-init per tile
    int aw0, aw1;           // A-frag LDS word offsets (within a head's tile)
    int mr, nc;             // C write coords
    bool sel16;             // permlane16_swap output select (probed)
    const float* gx[4];     // gl_lds sources (2 per head)
    float* op;
    float* ofin;
};

template<bool RM>
__device__ __forceinline__ void run_scan(Ctx cx, float hn,
                                         float (&xl)[2][1024],
                                         float (&wxT)[2][64][WPAD],
                                         int lane)
{
#define STAGE(nbuf, t0) do {                                                  \
        __builtin_amdgcn_global_load_lds((gas_t)(cx.gx[0] + (long)(t0) * ST), \
                                         (las_t)&xl[nbuf][0],   16, 0, 0);    \
        __builtin_amdgcn_global_load_lds((gas_t)(cx.gx[1] + (long)(t0) * ST), \
                                         (las_t)&xl[nbuf][256], 16, 0, 0);    \
        __builtin_amdgcn_global_load_lds((gas_t)(cx.gx[2] + (long)(t0) * ST), \
                                         (las_t)&xl[nbuf][512], 16, 0, 0);    \
        __builtin_amdgcn_global_load_lds((gas_t)(cx.gx[3] + (long)(t0) * ST), \
                                         (las_t)&xl[nbuf][768], 16, 0, 0);    \
    } while (0)

#define WX_TILE(nbuf, hs) do {                                                \
        float4 xa = *(const float4*)&xl[nbuf][(hs) * 512 + cx.aw0];           \
        float4 xc = *(const float4*)&xl[nbuf][(hs) * 512 + cx.aw1];           \
        AF af;                                                                \
        af.pcs[0] = __builtin_amdgcn_cvt_pkrtz(xa.x, xa.y);                   \
        af.pcs[1] = __builtin_amdgcn_cvt_pkrtz(xa.z, xa.w);                   \
        af.pcs[2] = __builtin_amdgcn_cvt_pkrtz(xc.x, xc.y);                   \
        af.pcs[3] = __builtin_amdgcn_cvt_pkrtz(xc.z, xc.w);                   \
        f32x4 c0 = {cx.bn[2*(hs)], cx.bn[2*(hs)], cx.bn[2*(hs)],              \
                    cx.bn[2*(hs)]};                                           \
        f32x4 c1 = {cx.bn[2*(hs)+1], cx.bn[2*(hs)+1], cx.bn[2*(hs)+1],        \
                    cx.bn[2*(hs)+1]};                                         \
        c0 = __builtin_amdgcn_mfma_f32_16x16x32_f16(af.v, cx.bf[2*(hs)].v,    \
                                                    c0, 0, 0, 0);             \
        c1 = __builtin_amdgcn_mfma_f32_16x16x32_f16(af.v, cx.bf[2*(hs)+1].v,  \
                                                    c1, 0, 0, 0);             \
        *(f32x4*)&wxT[nbuf][(hs) * 32 + cx.nc][cx.mr]      = c0;              \
        *(f32x4*)&wxT[nbuf][(hs) * 32 + cx.nc + 16][cx.mr] = c1;              \
    } while (0)

#define COMPUTE_WX(nbuf) do { WX_TILE(nbuf, 0); WX_TILE(nbuf, 1); } while (0)

// one scan step; WXV = this step's wx (register, quad component)
#define STEP(WXV) do {                                                        \
        const f16x2 pd = __builtin_amdgcn_cvt_pkrtz(hn, nexth<RM>(hn));       \
        const unsigned pdu = __builtin_bit_cast(unsigned, pd);                \
        const v2u po = __builtin_amdgcn_permlane16_swap(pdu, pdu,             \
                                                        false, false);        \
        const unsigned pou = cx.sel16 ? po.x : po.y;                          \
        const f16x2 pdo = __builtin_bit_cast(f16x2, pou);                     \
        float a0 = FDOT2(pd,               cx.wo[0], (WXV));                  \
        float a1 = FDOT2(rot2<RM, 4>(pdu), cx.wo[4], 0.0f);                   \
        a0 = FDOT2(rot2<RM, 1>(pdu), cx.wo[1], a0);                           \
        a1 = FDOT2(rot2<RM, 5>(pdu), cx.wo[5], a1);                           \
        a0 = FDOT2(rot2<RM, 2>(pdu), cx.wo[2], a0);                           \
        a1 = FDOT2(rot2<RM, 6>(pdu), cx.wo[6], a1);                           \
        a0 = FDOT2(rot2<RM, 3>(pdu), cx.wo[3], a0);                           \
        a1 = FDOT2(rot2<RM, 7>(pdu), cx.wo[7], a1);                           \
        float a2 = FDOT2(pdo,              cx.wt[0], 0.0f);                   \
        float a3 = FDOT2(rot2<RM, 4>(pou), cx.wt[4], 0.0f);                   \
        a2 = FDOT2(rot2<RM, 1>(pou), cx.wt[1], a2);                           \
        a3 = FDOT2(rot2<RM, 5>(pou), cx.wt[5], a3);                           \
        a2 = FDOT2(rot2<RM, 2>(pou), cx.wt[2], a2);                           \
        a3 = FDOT2(rot2<RM, 6>(pou), cx.wt[6], a3);                           \
        a2 = FDOT2(rot2<RM, 3>(pou), cx.wt[3], a2);                           \
        a3 = FDOT2(rot2<RM, 7>(pou), cx.wt[7], a3);                           \
        const float pre = (a0 + a1) + (a2 + a3);                              \
        hn = pre * __builtin_amdgcn_rcpf(1.0f + __builtin_fabsf(pre));        \
        op[0] = hn;                                                           \
        op += ST;                                                             \
    } while (0)

    // ---- prologue: block 0 ----
    STAGE(0, 0);
    asm volatile("s_waitcnt vmcnt(0)" ::: "memory");
    COMPUTE_WX(0);
    f32x4 wq = *(const f32x4*)&wxT[0][lane][0];     // quad for steps 0-3
    float* op = cx.op;

    for (int tb = 0; tb < T_STEPS; tb += BLK) {
        const int cur = (tb >> 4) & 1, nxt = cur ^ 1;
        const bool more = (tb + BLK) < T_STEPS;
        if (more) STAGE(nxt, tb + BLK);       // unsinkable gl_lds

        const float* wrow_cur = &wxT[cur][lane][0];
        const float* wrow_nxt = &wxT[nxt][lane][0];

        f32x4 wqn;
#pragma clang loop unroll(disable)
        for (int gq = 1; gq <= 3; ++gq) {
            wqn = *(const f32x4*)(wrow_cur + 4 * gq);
            STEP(wq[0]); STEP(wq[1]); STEP(wq[2]); STEP(wq[3]);
            wq = wqn;
        }

        // queue: [4 prev-group stores][4 gl_lds][12 stores] -> vmcnt(12)
        if (more) {
            asm volatile("s_waitcnt vmcnt(12)" ::: "memory");
            COMPUTE_WX(nxt);
        }

        // tail group + prefetch next block's quad 0 (garbage if !more, unused)
        wqn = *(const f32x4*)(wrow_nxt);
        STEP(wq[0]); STEP(wq[1]); STEP(wq[2]); STEP(wq[3]);
        wq = wqn;
    }

    cx.ofin[0] = hn;
#undef STEP
#undef STAGE
#undef COMPUTE_WX
#undef WX_TILE
}

__global__ __launch_bounds__(64, 1)
void elman_fused(const float* __restrict__ x,
                 const float* __restrict__ h0,
                 const float* __restrict__ R,
                 const float* __restrict__ Wx,
                 const float* __restrict__ bias,
                 float* __restrict__ out)
{
    const int l  = threadIdx.x & 63;
    const int c  = l & 15;               // pos within DPP row
    const int cc = l & 31;               // row this lane owns
    const int rb = (l >> 4) & 1;         // which 16-block my DPP row holds
    const int hp = blockIdx.x & 31;      // head pair
    const int b  = blockIdx.x >> 5;
    const int myhead = 2 * hp + (l >> 5);

    // ---- convention probes (R8-proven) ----
    const int pr = __builtin_amdgcn_update_dpp(l, l, 0x121, 0xF, 0xF, false);
    const bool ror_minus = ((pr & 15) == ((c - 1) & 15));
    const v2u pp = __builtin_amdgcn_permlane16_swap((unsigned)l, (unsigned)l,
                                                    false, false);

    Ctx cx;
    cx.sel16 = (pp.x == (unsigned)(l ^ 16));

    // ---- R weight pairs: own block jb = rb*16, other block jbo = 16-jb ----
    {
        const float* Rrow = R + (myhead * HD + cc) * HD;
        const int jb  = rb * 16;
        const int jbo = 16 - jb;
#pragma unroll
        for (int d = 0; d < 8; ++d) {
            const int s0 = (c + 2 * d) & 15;
            const int s1 = (s0 + 1) & 15;
            cx.wo[d] = __builtin_amdgcn_cvt_pkrtz(Rrow[jb + s0],  Rrow[jb + s1]);
            cx.wt[d] = __builtin_amdgcn_cvt_pkrtz(Rrow[jbo + s0], Rrow[jbo + s1]);
        }
    }

    // ---- MFMA B fragments for both heads (R10-proven layout) ----
    {
        const int n  = l & 15;
        const int k0 = (l >> 4) * 8;
#pragma unroll
        for (int t = 0; t < 4; ++t) {            // t = hs*2 + cb
            const int head = 2 * hp + (t >> 1);
            const int cb   = t & 1;
            const float4* wp =
                (const float4*)(Wx + (head * HD + cb * 16 + n) * HD + k0);
            float4 u = wp[0], v = wp[1];
            cx.bf[(t >> 1) * 2 + cb].pcs[0] = __builtin_amdgcn_cvt_pkrtz(u.x, u.y);
            cx.bf[(t >> 1) * 2 + cb].pcs[1] = __builtin_amdgcn_cvt_pkrtz(u.z, u.w);
            cx.bf[(t >> 1) * 2 + cb].pcs[2] = __builtin_amdgcn_cvt_pkrtz(v.x, v.y);
            cx.bf[(t >> 1) * 2 + cb].pcs[3] = __builtin_amdgcn_cvt_pkrtz(v.z, v.w);
            cx.bn[(t >> 1) * 2 + cb] = bias[head * HD + cb * 16 + n];
        }
        cx.mr = (l >> 4) * 4;
        cx.nc = n;
    }

    // A-frag LDS word offsets within a head tile (R10-proven)
    {
        const int J0 = (l >> 4) * 2, J1 = J0 + 1;
        cx.aw0 = 64 * (J0 & 3) + 4 * (l & 15) + 256 * (J0 >> 2);
        cx.aw1 = 64 * (J1 & 3) + 4 * (l & 15) + 256 * (J1 >> 2);
    }

    // gl_lds sources: 2 calls per head (R10-proven mapping per head)
    {
        const float* base = x + (long)(l & 15) * ST + (long)b * D_SZ
                              + (l >> 4) * 4;
        cx.gx[0] = base + (2 * hp)     * HD;
        cx.gx[1] = cx.gx[0] + 16;
        cx.gx[2] = base + (2 * hp + 1) * HD;
        cx.gx[3] = cx.gx[2] + 16;
    }

    cx.op   = out + (long)b * D_SZ + hp * 64 + l;    // coalesced 64-dword row
    cx.ofin = out + (long)T_STEPS * ST + (long)b * H_SZ * HD + hp * 64 + l;

    const float hn = h0[b * H_SZ * HD + hp * 64 + l];

    __shared__ __align__(16) float xl[2][1024];
    __shared__ __align__(16) float wxT[2][64][WPAD];

    if (ror_minus) run_scan<true>(cx, hn, xl, wxT, l);
    else           run_scan<false>(cx, hn, xl, wxT, l);
}

extern "C" void kernel_launch(void* const* d_in, const int* in_sizes, int n_in,
                              void* d_out, int out_size, void* d_ws, size_t ws_size,
                              hipStream_t stream) {
    const float* x    = (const float*)d_in[0];
    const float* h0   = (const float*)d_in[1];
    const float* R    = (const float*)d_in[2];
    const float* Wx   = (const float*)d_in[3];
    const float* bias = (const float*)d_in[4];
    float* out = (float*)d_out;

    elman_fused<<<dim3(B_SZ * (H_SZ / 2)), dim3(64), 0, stream>>>(
        x, h0, R, Wx, bias, out);
}

// Round 16
// 562.814 us; speedup vs baseline: 1.2629x; 1.2629x over previous
//
#include <hip/hip_runtime.h>

// MultiHeadElman scan, R16: the recurrence IS the MFMA.
// h' = softsign(R@h + wx). Per chain (one 64-lane wave), per step:
//   B-frag = h replicated over columns: lane (n=l&15, kh=g=l>>4) needs
//            B[8g+i][n] = h[8g+i] -- built from the lane's OWN 8 h values.
//   A-frag = R with PERMUTED rows: tile0 rows pi0(m)=(m>>2)*8+(m&3),
//            tile1 rows pi0(m)+4 (static, loaded once).
//   C-init = wx quads (f32, exact).   C-out: lane (n,g) holds
//            y[pi0(4g+j)] = y[8g+j] (tile0) and y[8g+4+j] (tile1)
//            == exactly the h[8g..8g+7] the next step's B-frag needs.
// => ZERO cross-lane ops in the scan step: 4 cvt_pkrtz -> 2 MFMA ->
//    8 in-lane softsigns -> 2 coalesced stores. (The MFMA does the
//    cross-lane work internally.)
// wx projection per 16-step block: two mfma_f32_16x16x32_f16 (R10-proven
// layouts), x staged via global_load_lds + counted vmcnt (R12-proven).
// wx quads: 2-set ping-pong register pipeline, ds_read_b128 a quarter-block
// (4 steps ~ 600cy) ahead of use.

typedef __fp16 f16x2 __attribute__((ext_vector_type(2)));
typedef __fp16 f16x8 __attribute__((ext_vector_type(8)));
typedef float  f32x4 __attribute__((ext_vector_type(4)));

constexpr int T_STEPS = 4096;
constexpr int B_SZ    = 4;
constexpr int D_SZ    = 2048;
constexpr int H_SZ    = 64;
constexpr int HD      = 32;
constexpr long ST     = (long)B_SZ * D_SZ;   // 8192 floats per t
constexpr int BLK     = 16;                  // steps per block

typedef const __attribute__((address_space(1))) void* gas_t;
typedef __attribute__((address_space(3))) void*       las_t;

union AF { f16x8 v; f16x2 pcs[4]; };

__global__ __launch_bounds__(64, 1)
void elman_fused(const float* __restrict__ x,
                 const float* __restrict__ h0v,
                 const float* __restrict__ R,
                 const float* __restrict__ Wx,
                 const float* __restrict__ bias,
                 float* __restrict__ out)
{
    const int l = threadIdx.x & 63;
    const int n = l & 15;                // column index (replicated dim)
    const int g = l >> 4;                // row-group == B-frag kh
    const int h = blockIdx.x & (H_SZ - 1);
    const int b = blockIdx.x >> 6;
    const int col8 = 8 * g;              // this lane's h-slice start

    // ---- recurrence A-fragments (static): permuted R rows, f16 ----
    // lane (m=n, kh=g) holds A[m][8g+i] = R[pi(m)][8g+i]
    AF ra0, ra1;
    {
        const int m  = n;
        const int p0 = (m >> 2) * 8 + (m & 3);      // tile0 row
        const float* r0 = R + (h * HD + p0) * HD + 8 * g;
        const float* r1 = R + (h * HD + p0 + 4) * HD + 8 * g;
        float4 u = *(const float4*)r0, v = *(const float4*)(r0 + 4);
        ra0.pcs[0] = __builtin_amdgcn_cvt_pkrtz(u.x, u.y);
        ra0.pcs[1] = __builtin_amdgcn_cvt_pkrtz(u.z, u.w);
        ra0.pcs[2] = __builtin_amdgcn_cvt_pkrtz(v.x, v.y);
        ra0.pcs[3] = __builtin_amdgcn_cvt_pkrtz(v.z, v.w);
        u = *(const float4*)r1; v = *(const float4*)(r1 + 4);
        ra1.pcs[0] = __builtin_amdgcn_cvt_pkrtz(u.x, u.y);
        ra1.pcs[1] = __builtin_amdgcn_cvt_pkrtz(u.z, u.w);
        ra1.pcs[2] = __builtin_amdgcn_cvt_pkrtz(v.x, v.y);
        ra1.pcs[3] = __builtin_amdgcn_cvt_pkrtz(v.z, v.w);
    }

    // ---- wx-projection fragments (R10/R12-proven, bias FULL scale) ----
    AF bfW0, bfW1;
    {
        const float4* wp0 = (const float4*)(Wx + (h * HD + n) * HD + 8 * g);
        const float4* wp1 = (const float4*)(Wx + (h * HD + n + 16) * HD + 8 * g);
        float4 u = wp0[0], v = wp0[1];
        bfW0.pcs[0] = __builtin_amdgcn_cvt_pkrtz(u.x, u.y);
        bfW0.pcs[1] = __builtin_amdgcn_cvt_pkrtz(u.z, u.w);
        bfW0.pcs[2] = __builtin_amdgcn_cvt_pkrtz(v.x, v.y);
        bfW0.pcs[3] = __builtin_amdgcn_cvt_pkrtz(v.z, v.w);
        u = wp1[0]; v = wp1[1];
        bfW1.pcs[0] = __builtin_amdgcn_cvt_pkrtz(u.x, u.y);
        bfW1.pcs[1] = __builtin_amdgcn_cvt_pkrtz(u.z, u.w);
        bfW1.pcs[2] = __builtin_amdgcn_cvt_pkrtz(v.x, v.y);
        bfW1.pcs[3] = __builtin_amdgcn_cvt_pkrtz(v.z, v.w);
    }
    const float bn0 = bias[h * HD + n];
    const float bn1 = bias[h * HD + n + 16];
    const int   mr  = g * 4;

    // ---- h state: this lane's 8 values h[8g..8g+7] ----
    float hh[8];
    {
        const float* hp = h0v + (b * H_SZ + h) * HD + col8;
        float4 u = *(const float4*)hp, v = *(const float4*)(hp + 4);
        hh[0] = u.x; hh[1] = u.y; hh[2] = u.z; hh[3] = u.w;
        hh[4] = v.x; hh[5] = v.y; hh[6] = v.z; hh[7] = v.w;
    }

    __shared__ __align__(16) float xl[2][512];      // x tiles (gl_lds linear)
    __shared__ __align__(16) float wxl[2][BLK][32]; // wx tiles, step-major

    // A-frag LDS word offsets for the wx MFMA (R10-proven)
    const int J0 = g * 2, J1 = J0 + 1;
    const int aw0 = 64 * (J0 & 3) + 4 * n + 256 * (J0 >> 2);
    const int aw1 = 64 * (J1 & 3) + 4 * n + 256 * (J1 >> 2);

    const float* gx0 = x + (long)n * ST + (long)b * D_SZ + h * HD + g * 4;
    const float* gx1 = gx0 + 16;

    float* op = out + (long)b * D_SZ + h * HD + col8;

#define STAGE(nbuf, t0) do {                                                  \
        __builtin_amdgcn_global_load_lds((gas_t)(gx0 + (long)(t0) * ST),      \
                                         (las_t)&xl[nbuf][0],   16, 0, 0);    \
        __builtin_amdgcn_global_load_lds((gas_t)(gx1 + (long)(t0) * ST),      \
                                         (las_t)&xl[nbuf][256], 16, 0, 0);    \
    } while (0)

#define COMPUTE_WX(nbuf) do {                                                 \
        float4 xa = *(const float4*)&xl[nbuf][aw0];                           \
        float4 xc = *(const float4*)&xl[nbuf][aw1];                           \
        AF af;                                                                \
        af.pcs[0] = __builtin_amdgcn_cvt_pkrtz(xa.x, xa.y);                   \
        af.pcs[1] = __builtin_amdgcn_cvt_pkrtz(xa.z, xa.w);                   \
        af.pcs[2] = __builtin_amdgcn_cvt_pkrtz(xc.x, xc.y);                   \
        af.pcs[3] = __builtin_amdgcn_cvt_pkrtz(xc.z, xc.w);                   \
        f32x4 c0 = {bn0, bn0, bn0, bn0};                                      \
        f32x4 c1 = {bn1, bn1, bn1, bn1};                                      \
        c0 = __builtin_amdgcn_mfma_f32_16x16x32_f16(af.v, bfW0.v, c0, 0,0,0); \
        c1 = __builtin_amdgcn_mfma_f32_16x16x32_f16(af.v, bfW1.v, c1, 0,0,0); \
        wxl[nbuf][mr + 0][n] = c0[0]; wxl[nbuf][mr + 0][n + 16] = c1[0];      \
        wxl[nbuf][mr + 1][n] = c0[1]; wxl[nbuf][mr + 1][n + 16] = c1[1];      \
        wxl[nbuf][mr + 2][n] = c0[2]; wxl[nbuf][mr + 2][n + 16] = c1[2];      \
        wxl[nbuf][mr + 3][n] = c0[3]; wxl[nbuf][mr + 3][n + 16] = c1[3];      \
    } while (0)

// one scan step; QLO/QHI: wx quads (f32x4) = C-init
#define ONESTEP(QLO, QHI) do {                                                \
        AF bu;                                                                \
        bu.pcs[0] = __builtin_amdgcn_cvt_pkrtz(hh[0], hh[1]);                 \
        bu.pcs[1] = __builtin_amdgcn_cvt_pkrtz(hh[2], hh[3]);                 \
        bu.pcs[2] = __builtin_amdgcn_cvt_pkrtz(hh[4], hh[5]);                 \
        bu.pcs[3] = __builtin_amdgcn_cvt_pkrtz(hh[6], hh[7]);                 \
        f32x4 c0 = __builtin_amdgcn_mfma_f32_16x16x32_f16(ra0.v, bu.v,        \
                                                          (QLO), 0, 0, 0);    \
        f32x4 c1 = __builtin_amdgcn_mfma_f32_16x16x32_f16(ra1.v, bu.v,        \
                                                          (QHI), 0, 0, 0);    \
        _Pragma("unroll")                                                     \
        for (int j = 0; j < 4; ++j) {                                         \
            hh[j]     = c0[j] *                                               \
                __builtin_amdgcn_rcpf(1.0f + __builtin_fabsf(c0[j]));         \
            hh[4 + j] = c1[j] *                                               \
                __builtin_amdgcn_rcpf(1.0f + __builtin_fabsf(c1[j]));         \
        }                                                                     \
        float4 s0 = {hh[0], hh[1], hh[2], hh[3]};                             \
        float4 s1 = {hh[4], hh[5], hh[6], hh[7]};                             \
        *(float4*)op = s0; *(float4*)(op + 4) = s1;                           \
        op += ST;                                                             \
    } while (0)

// quarter: read next 4 steps' quads into DEST, run 4 steps consuming CONS
#define QUARTER(CONS, DEST, RBASE, ROW0) do {                                 \
        _Pragma("unroll")                                                     \
        for (int r = 0; r < 4; ++r) {                                         \
            DEST[2*r]   = *(const f32x4*)((RBASE) + ((ROW0)+r)*32 + col8);    \
            DEST[2*r+1] = *(const f32x4*)((RBASE) + ((ROW0)+r)*32 + col8+4);  \
        }                                                                     \
        ONESTEP(CONS[0], CONS[1]);                                            \
        ONESTEP(CONS[2], CONS[3]);                                            \
        ONESTEP(CONS[4], CONS[5]);                                            \
        ONESTEP(CONS[6], CONS[7]);                                            \
    } while (0)

    // ---- prologue: block 0, fill SA with steps 0-3 ----
    STAGE(0, 0);
    asm volatile("s_waitcnt vmcnt(0)" ::: "memory");
    COMPUTE_WX(0);
    f32x4 SA[8], SB[8];
#pragma unroll
    for (int r = 0; r < 4; ++r) {
        SA[2*r]   = *(const f32x4*)(&wxl[0][0][0] + r*32 + col8);
        SA[2*r+1] = *(const f32x4*)(&wxl[0][0][0] + r*32 + col8 + 4);
    }

    for (int tb = 0; tb < T_STEPS; tb += BLK) {
        const int cur = (tb >> 4) & 1, nxt = cur ^ 1;
        const bool more = (tb + BLK) < T_STEPS;
        if (more) STAGE(nxt, tb + BLK);       // unsinkable gl_lds

        const float* wb_cur = &wxl[cur][0][0];
        const float* wb_las = more ? &wxl[nxt][0][0] : wb_cur;

        QUARTER(SA, SB, wb_cur, 4);    // steps  0-3, read rows  4-7
        QUARTER(SB, SA, wb_cur, 8);    // steps  4-7, read rows  8-11
        QUARTER(SA, SB, wb_cur, 12);   // steps  8-11, read rows 12-15

        if (more) {
            // queue: [2 gl_lds][24 stores from 12 steps] -> vmcnt(24)
            asm volatile("s_waitcnt vmcnt(24)" ::: "memory");
            COMPUTE_WX(nxt);
        }

        QUARTER(SB, SA, wb_las, 0);    // steps 12-15, read next block 0-3
    }

    // h_final (16-way duplicate stores, identical values)
    {
        float* fp = out + (long)T_STEPS * ST + (b * H_SZ + h) * HD + col8;
        float4 s0 = {hh[0], hh[1], hh[2], hh[3]};
        float4 s1 = {hh[4], hh[5], hh[6], hh[7]};
        *(float4*)fp = s0; *(float4*)(fp + 4) = s1;
    }
#undef QUARTER
#undef ONESTEP
#undef STAGE
#undef COMPUTE_WX
}

extern "C" void kernel_launch(void* const* d_in, const int* in_sizes, int n_in,
                              void* d_out, int out_size, void* d_ws, size_t ws_size,
                              hipStream_t stream) {
    const float* x    = (const float*)d_in[0];
    const float* h0   = (const float*)d_in[1];
    const float* R    = (const float*)d_in[2];
    const float* Wx   = (const float*)d_in[3];
    const float* bias = (const float*)d_in[4];
    float* out = (float*)d_out;

    elman_fused<<<dim3(B_SZ * H_SZ), dim3(64), 0, stream>>>(
        x, h0, R, Wx, bias, out);
}